// Round 1
// baseline (1765.709 us; speedup 1.0000x reference)
//
#include <hip/hip_runtime.h>
#include <math.h>

#define NB 262144
#define ND 128
#define NL 8

typedef __bf16 bf16x8 __attribute__((ext_vector_type(8)));
typedef float  f32x4  __attribute__((ext_vector_type(4)));

union BFP { unsigned int u; __bf16 h[2]; unsigned short s[2]; };

__device__ __forceinline__ float sigm(float x){ return 1.0f/(1.0f + __expf(-x)); }
__device__ __forceinline__ float tanhfast(float x){
  float t = __expf(-2.0f*fabsf(x));
  return copysignf((1.0f - t)/(1.0f + t), x);
}
__device__ __forceinline__ float red16(float v){
  v += __shfl_xor(v, 1);
  v += __shfl_xor(v, 2);
  v += __shfl_xor(v, 4);
  v += __shfl_xor(v, 8);
  return v;
}
__device__ __forceinline__ unsigned short bfbits(float f){
  BFP x; x.h[0] = (__bf16)f; return x.s[0];
}
__device__ __forceinline__ unsigned int pk2(float a, float b){
  BFP x; x.h[0]=(__bf16)a; x.h[1]=(__bf16)b; return x.u;
}
__device__ __forceinline__ void gload16(const void* g, void* s){
  __builtin_amdgcn_global_load_lds((const __attribute__((address_space(1))) unsigned int*)g,
                                   (__attribute__((address_space(3))) unsigned int*)s,
                                   16, 0, 0);
}

// ---- prep 1: repack Wg/Wp (fp32, [L][256][128]) into bf16 B-fragment order ----
// dst layout: [(l*2+mat)][kf(8)][cf(8)][lane(64)] x 16B ; mat 0 = Wg, 1 = Wp
__global__ void repack_w(const float* __restrict__ Wp, const float* __restrict__ Wg,
                         uint4* __restrict__ dst){
  int t = blockIdx.x*256 + threadIdx.x;      // 65536 threads
  int lane = t & 63;
  int frag = t >> 6;                          // 1024 frags
  int cf = frag & 7, kf = (frag >> 3) & 7, mat = (frag >> 6) & 1, l = frag >> 7;
  const float* W = mat ? Wp : Wg;
  int k = kf*32 + (lane >> 4)*8;
  int n = cf*16 + (lane & 15);
  const float* src = W + (l*256 + k)*ND + n;
  bf16x8 v;
#pragma unroll
  for (int j=0;j<8;++j) v[j] = (__bf16)src[j*ND];
  dst[((l*2 + mat)*64 + kf*8 + cf)*64 + lane] = __builtin_bit_cast(uint4, v);
}

// ---- prep 2: prevdot[row][l] = previous[row] . Ws_l[128:256] + bs_l ----
__global__ void prevdot_k(const float* __restrict__ previous, const float* __restrict__ Ws,
                          const float* __restrict__ bs, float* __restrict__ pdot){
  int t = blockIdx.x*256 + threadIdx.x;
  int row = t >> 4, g = t & 15;
  const float* p = previous + (size_t)row*ND + g*8;
  float4 a = *(const float4*)p;
  float4 b = *(const float4*)(p+4);
#pragma unroll
  for (int l=0;l<NL;++l){
    const float* w = Ws + l*256 + 128 + g*8;
    float s = a.x*w[0] + a.y*w[1] + a.z*w[2] + a.w*w[3]
            + b.x*w[4] + b.y*w[5] + b.z*w[6] + b.w*w[7];
    s += __shfl_xor(s,1); s += __shfl_xor(s,2); s += __shfl_xor(s,4); s += __shfl_xor(s,8);
    if (g==0) pdot[row*NL + l] = s + bs[l];
  }
}

// ---- main fused kernel: 512 threads, 256 rows/block, 8 levels in registers ----
__global__ __launch_bounds__(512, 1)
void fused_k(const float* __restrict__ signal, const float* __restrict__ previous,
             const float* __restrict__ bp, const float* __restrict__ bg,
             const float* __restrict__ Ws, const float* __restrict__ gamma,
             const float* __restrict__ beta,
             const uint4* __restrict__ wpk, const float* __restrict__ pdot,
             float* __restrict__ out)
{
  __shared__ unsigned short tile[256*128];   // 64KB: current tile, bf16, XOR-swizzled
  __shared__ uint4 wbuf[4096];               // 64KB: one weight matrix in B-frag order

  const int tid  = threadIdx.x;
  const int w    = tid >> 6;
  const int lane = tid & 63;
  const int llo  = lane & 15;
  const int lhi  = lane >> 4;
  const int rbase = w * 32;
  const int row0  = blockIdx.x * 256;

  // previous half of joined, as persistent A-fragments (K slots 128..255)
  bf16x8 prevA[2][4];
#pragma unroll
  for (int rf=0; rf<2; ++rf){
    int row = row0 + rbase + rf*16 + llo;
#pragma unroll
    for (int kf=0; kf<4; ++kf){
      const float* p = previous + (size_t)row*ND + kf*32 + lhi*8;
      float4 f0 = *(const float4*)p;
      float4 f1 = *(const float4*)(p+4);
      bf16x8 v;
      v[0]=(__bf16)f0.x; v[1]=(__bf16)f0.y; v[2]=(__bf16)f0.z; v[3]=(__bf16)f0.w;
      v[4]=(__bf16)f1.x; v[5]=(__bf16)f1.y; v[6]=(__bf16)f1.z; v[7]=(__bf16)f1.w;
      prevA[rf][kf] = v;
    }
  }

  float curC[2][8][4];        // current, C-layout, fp32 master
  f32x4 accv[2][8];           // accumulated output
  float active[2][4], depth[2][4], smass[2][4], gsum[2][4], dsum[2][4], asum[2][4];
#pragma unroll
  for (int rf=0; rf<2; ++rf){
#pragma unroll
    for (int cf=0; cf<8; ++cf){
      accv[rf][cf] = (f32x4){0.f,0.f,0.f,0.f};
#pragma unroll
      for (int r=0; r<4; ++r){
        int row = row0 + rbase + rf*16 + lhi*4 + r;
        curC[rf][cf][r] = signal[(size_t)row*ND + cf*16 + llo];
      }
    }
#pragma unroll
    for (int r=0; r<4; ++r){
      active[rf][r]=1.f; depth[rf][r]=0.f; smass[rf][r]=0.f;
      gsum[rf][r]=0.f; dsum[rf][r]=0.f; asum[rf][r]=0.f;
    }
  }

#pragma unroll 1
  for (int l=0; l<NL; ++l){
    // stage Wg (slot 2l) into wbuf
    {
      const char* src = (const char*)wpk + (size_t)(l*2 + 0)*65536;
      char* dstb = (char*)wbuf;
#pragma unroll
      for (int i=0;i<8;++i){
        int off = i*8192 + tid*16;
        gload16(src + off, dstb + off);
      }
    }
    // write current into tile (bf16, swizzled: byte ^= (row&7)<<4)
#pragma unroll
    for (int rf=0; rf<2; ++rf)
#pragma unroll
      for (int cf=0; cf<8; ++cf)
#pragma unroll
        for (int r=0; r<4; ++r){
          int rowl = rbase + rf*16 + lhi*4 + r;
          int byte = ((cf*16 + llo)*2) ^ ((rowl & 7) << 4);
          tile[rowl*128 + (byte>>1)] = bfbits(curC[rf][cf][r]);
        }
    __syncthreads();                       // S1: tile + Wg ready

    // read current A-fragments (K slots 0..127)
    bf16x8 curA[2][4];
#pragma unroll
    for (int rf=0; rf<2; ++rf){
      int rowl = rbase + rf*16 + llo;
      const char* base = (const char*)tile + rowl*256;
      int sw = (rowl & 7) << 4;
#pragma unroll
      for (int kf=0; kf<4; ++kf){
        int byte = (kf*64 + lhi*16) ^ sw;
        curA[rf][kf] = __builtin_bit_cast(bf16x8, *(const uint4*)(base + byte));
      }
    }

    f32x4 pacc[2][8];
    auto zero_acc = [&](){
#pragma unroll
      for (int rf=0; rf<2; ++rf)
#pragma unroll
        for (int cf=0; cf<8; ++cf) pacc[rf][cf] = (f32x4){0.f,0.f,0.f,0.f};
    };
    auto run_gemm = [&](){
#pragma unroll
      for (int kf=0; kf<4; ++kf){
        bf16x8 a0 = curA[0][kf], a1 = curA[1][kf];
#pragma unroll
        for (int cf=0; cf<8; ++cf){
          bf16x8 b = __builtin_bit_cast(bf16x8, wbuf[(kf*8+cf)*64 + lane]);
          pacc[0][cf] = __builtin_amdgcn_mfma_f32_16x16x32_bf16(a0, b, pacc[0][cf], 0,0,0);
          pacc[1][cf] = __builtin_amdgcn_mfma_f32_16x16x32_bf16(a1, b, pacc[1][cf], 0,0,0);
        }
      }
#pragma unroll
      for (int kp=0; kp<4; ++kp){
        bf16x8 a0 = prevA[0][kp], a1 = prevA[1][kp];
#pragma unroll
        for (int cf=0; cf<8; ++cf){
          bf16x8 b = __builtin_bit_cast(bf16x8, wbuf[((kp+4)*8+cf)*64 + lane]);
          pacc[0][cf] = __builtin_amdgcn_mfma_f32_16x16x32_bf16(a0, b, pacc[0][cf], 0,0,0);
          pacc[1][cf] = __builtin_amdgcn_mfma_f32_16x16x32_bf16(a1, b, pacc[1][cf], 0,0,0);
        }
      }
    };

    // ---- gate GEMM ----
    zero_acc();
    run_gemm();

    unsigned int gstash[2][8][2];
    {
      float gpart[2][4] = {{0.f,0.f,0.f,0.f},{0.f,0.f,0.f,0.f}};
#pragma unroll
      for (int cf=0; cf<8; ++cf){
        float bgv = bg[l*ND + cf*16 + llo];
#pragma unroll
        for (int rf=0; rf<2; ++rf){
          float g0 = sigm(pacc[rf][cf][0] + bgv);
          float g1 = sigm(pacc[rf][cf][1] + bgv);
          float g2 = sigm(pacc[rf][cf][2] + bgv);
          float g3 = sigm(pacc[rf][cf][3] + bgv);
          gpart[rf][0]+=g0; gpart[rf][1]+=g1; gpart[rf][2]+=g2; gpart[rf][3]+=g3;
          gstash[rf][cf][0] = pk2(g0,g1);
          gstash[rf][cf][1] = pk2(g2,g3);
        }
      }
#pragma unroll
      for (int rf=0; rf<2; ++rf)
#pragma unroll
        for (int r=0; r<4; ++r)
          gsum[rf][r] += red16(gpart[rf][r]) * (1.0f/ND);
    }
    __syncthreads();                       // S2: everyone done reading Wg
    // stage Wp (slot 2l+1)
    {
      const char* src = (const char*)wpk + (size_t)(l*2 + 1)*65536;
      char* dstb = (char*)wbuf;
#pragma unroll
      for (int i=0;i<8;++i){
        int off = i*8192 + tid*16;
        gload16(src + off, dstb + off);
      }
    }
    __syncthreads();                       // S3: Wp ready

    // ---- candidate GEMM ----
    zero_acc();
    run_gemm();

    // ---- elementwise update + LN + stats ----
    float s1[2][4] = {{0.f,0.f,0.f,0.f},{0.f,0.f,0.f,0.f}};
    float s2[2][4] = {{0.f,0.f,0.f,0.f},{0.f,0.f,0.f,0.f}};
#pragma unroll
    for (int cf=0; cf<8; ++cf){
      float bpv = bp[l*ND + cf*16 + llo];
#pragma unroll
      for (int rf=0; rf<2; ++rf){
#pragma unroll
        for (int r=0; r<4; ++r){
          float cand = tanhfast(pacc[rf][cf][r] + bpv);
          float c = curC[rf][cf][r];
          BFP gp; gp.u = gstash[rf][cf][r>>1];
          float g = (float)gp.h[r&1];
          float x = c + g*(cand - c);
          pacc[rf][cf][r] = x;
          s1[rf][r] += x; s2[rf][r] += x*x;
        }
      }
    }
    float mu[2][4], inv[2][4];
#pragma unroll
    for (int rf=0; rf<2; ++rf)
#pragma unroll
      for (int r=0; r<4; ++r){
        float m = red16(s1[rf][r]) * (1.0f/ND);
        float q = red16(s2[rf][r]) * (1.0f/ND);
        mu[rf][r] = m;
        inv[rf][r] = rsqrtf(q - m*m + 1e-5f);
      }
    float dpart[2][4] = {{0.f,0.f,0.f,0.f},{0.f,0.f,0.f,0.f}};
    float apart[2][4] = {{0.f,0.f,0.f,0.f},{0.f,0.f,0.f,0.f}};
#pragma unroll
    for (int cf=0; cf<8; ++cf){
      float gm = gamma[l*ND + cf*16 + llo];
      float bt = beta [l*ND + cf*16 + llo];
      float wv = Ws[l*256 + cf*16 + llo];
#pragma unroll
      for (int rf=0; rf<2; ++rf)
#pragma unroll
        for (int r=0; r<4; ++r){
          float un = (pacc[rf][cf][r] - mu[rf][r])*inv[rf][r]*gm + bt;
          float c = curC[rf][cf][r];
          float df = un - c;
          dpart[rf][r] += df*df;
          apart[rf][r] += un*wv;
          pacc[rf][cf][r] = un;
        }
    }
    float smrow[2][4];
#pragma unroll
    for (int rf=0; rf<2; ++rf)
#pragma unroll
      for (int r=0; r<4; ++r){
        float dd = red16(dpart[rf][r]);
        float av = red16(apart[rf][r]);
        int row = row0 + rbase + rf*16 + lhi*4 + r;
        float adq = sigm(av + pdot[row*NL + l]);
        float sp  = sigm((adq - 0.6f)*10.0f);
        float sm  = active[rf][r]*sp;
        asum[rf][r] += adq;
        dsum[rf][r] += sqrtf(dd);
        depth[rf][r] += sm * (float)(l+1);
        smass[rf][r] += sm;
        active[rf][r] *= (1.0f - sp);
        smrow[rf][r] = sm;
      }
#pragma unroll
    for (int rf=0; rf<2; ++rf)
#pragma unroll
      for (int cf=0; cf<8; ++cf)
#pragma unroll
        for (int r=0; r<4; ++r){
          float un = pacc[rf][cf][r];
          accv[rf][cf][r] += smrow[rf][r]*un;
          curC[rf][cf][r] = un;
        }
    __syncthreads();                       // S4: wbuf & tile free for next level
  }

  // ---- outputs ----
#pragma unroll
  for (int rf=0; rf<2; ++rf)
#pragma unroll
    for (int cf=0; cf<8; ++cf)
#pragma unroll
      for (int r=0; r<4; ++r){
        int row = row0 + rbase + rf*16 + lhi*4 + r;
        out[(size_t)row*ND + cf*16 + llo] = accv[rf][cf][r] + active[rf][r]*curC[rf][cf][r];
      }
  if (llo == 0){
    const size_t BD = (size_t)NB*ND;
#pragma unroll
    for (int rf=0; rf<2; ++rf)
#pragma unroll
      for (int r=0; r<4; ++r){
        int row = row0 + rbase + rf*16 + lhi*4 + r;
        out[BD + row]            = gsum[rf][r]*(1.0f/NL);
        out[BD + NB + row]       = dsum[rf][r]*(1.0f/NL);
        out[BD + 2*(size_t)NB + row] = depth[rf][r] + active[rf][r]*(float)NL;
        out[BD + 3*(size_t)NB + row] = smass[rf][r];
        out[BD + 4*(size_t)NB + row] = asum[rf][r]*(1.0f/NL);
      }
  }
}

extern "C" void kernel_launch(void* const* d_in, const int* in_sizes, int n_in,
                              void* d_out, int out_size, void* d_ws, size_t ws_size,
                              hipStream_t stream){
  const float* signal   = (const float*)d_in[0];
  const float* previous = (const float*)d_in[1];
  const float* Wp    = (const float*)d_in[2];
  const float* bp    = (const float*)d_in[3];
  const float* Wg    = (const float*)d_in[4];
  const float* bg    = (const float*)d_in[5];
  const float* Ws    = (const float*)d_in[6];
  const float* bs    = (const float*)d_in[7];
  const float* gamma = (const float*)d_in[8];
  const float* beta  = (const float*)d_in[9];

  uint4* wpk  = (uint4*)d_ws;                                   // 1 MB packed weights
  float* pdot = (float*)((char*)d_ws + (size_t)NL*2*65536);     // 8 MB prevdot

  repack_w<<<256, 256, 0, stream>>>(Wp, Wg, wpk);
  prevdot_k<<<NB/16, 256, 0, stream>>>(previous, Ws, bs, pdot);
  fused_k<<<NB/256, 512, 0, stream>>>(signal, previous, bp, bg, Ws, gamma, beta,
                                      wpk, pdot, (float*)d_out);
}

// Round 2
// 944.685 us; speedup vs baseline: 1.8691x; 1.8691x over previous
//
#include <hip/hip_runtime.h>
#include <math.h>

#define NB 262144
#define ND 128
#define NL 8

typedef __bf16 bf16x8 __attribute__((ext_vector_type(8)));
typedef float  f32x4  __attribute__((ext_vector_type(4)));

union BFP { unsigned int u; __bf16 h[2]; unsigned short s[2]; };

__device__ __forceinline__ float sigm(float x){ return 1.0f/(1.0f + __expf(-x)); }
__device__ __forceinline__ float tanhfast(float x){
  float t = __expf(-2.0f*fabsf(x));
  return copysignf((1.0f - t)/(1.0f + t), x);
}
__device__ __forceinline__ float red16(float v){
  v += __shfl_xor(v, 1);
  v += __shfl_xor(v, 2);
  v += __shfl_xor(v, 4);
  v += __shfl_xor(v, 8);
  return v;
}
__device__ __forceinline__ unsigned short bfbits(float f){
  BFP x; x.h[0] = (__bf16)f; return x.s[0];
}
__device__ __forceinline__ unsigned int pk2(float a, float b){
  BFP x; x.h[0]=(__bf16)a; x.h[1]=(__bf16)b; return x.u;
}
__device__ __forceinline__ void gload16(const void* g, void* s){
  __builtin_amdgcn_global_load_lds((const __attribute__((address_space(1))) unsigned int*)g,
                                   (__attribute__((address_space(3))) unsigned int*)s,
                                   16, 0, 0);
}

// ---- prep 1: repack Wg/Wp (fp32, [L][256][128]) into bf16 B-fragment order ----
// dst layout: [(l*2+mat)][kf(8)][cf(8)][lane(64)] x 16B ; mat 0 = Wg, 1 = Wp
__global__ void repack_w(const float* __restrict__ Wp, const float* __restrict__ Wg,
                         uint4* __restrict__ dst){
  int t = blockIdx.x*256 + threadIdx.x;      // 65536 threads
  int lane = t & 63;
  int frag = t >> 6;                          // 1024 frags
  int cf = frag & 7, kf = (frag >> 3) & 7, mat = (frag >> 6) & 1, l = frag >> 7;
  const float* W = mat ? Wp : Wg;
  int k = kf*32 + (lane >> 4)*8;
  int n = cf*16 + (lane & 15);
  const float* src = W + (l*256 + k)*ND + n;
  bf16x8 v;
#pragma unroll
  for (int j=0;j<8;++j) v[j] = (__bf16)src[j*ND];
  dst[((l*2 + mat)*64 + kf*8 + cf)*64 + lane] = __builtin_bit_cast(uint4, v);
}

// ---- prep 2: pdot[row][l] = previous[row] . Ws_l[128:256] + bs_l (fp32) ----
__global__ void prevdot_k(const float* __restrict__ previous, const float* __restrict__ Ws,
                          const float* __restrict__ bs, float* __restrict__ pdot){
  int t = blockIdx.x*256 + threadIdx.x;
  int row = t >> 4, g = t & 15;
  const float* p = previous + (size_t)row*ND + g*8;
  float4 a = *(const float4*)p;
  float4 b = *(const float4*)(p+4);
#pragma unroll
  for (int l=0;l<NL;++l){
    const float* w = Ws + l*256 + 128 + g*8;
    float s = a.x*w[0] + a.y*w[1] + a.z*w[2] + a.w*w[3]
            + b.x*w[4] + b.y*w[5] + b.z*w[6] + b.w*w[7];
    s += __shfl_xor(s,1); s += __shfl_xor(s,2); s += __shfl_xor(s,4); s += __shfl_xor(s,8);
    if (g==0) pdot[row*NL + l] = s + bs[l];
  }
}

// ---- main fused kernel: 256 threads, 4 waves x 16 rows, no spill ----
__global__ __launch_bounds__(256, 2)
void fused_k(const float* __restrict__ signal, const float* __restrict__ previous,
             const float* __restrict__ bp, const float* __restrict__ bg,
             const float* __restrict__ Ws, const float* __restrict__ gamma,
             const float* __restrict__ beta,
             const uint4* __restrict__ wpk, const float* __restrict__ pdot,
             float* __restrict__ out)
{
  __shared__ unsigned short tile[64*128];    // 16KB: current tile, bf16, XOR-swizzled, wave-private rows
  __shared__ uint4 wbuf[4096];               // 64KB: one weight matrix in B-frag order

  const int tid  = threadIdx.x;
  const int w    = tid >> 6;
  const int lane = tid & 63;
  const int llo  = lane & 15;
  const int lhi  = lane >> 4;
  const int rbase = w * 16;
  const int row0  = blockIdx.x * 64;

  // previous half of joined, as persistent A-fragments (K slots 128..255)
  bf16x8 prevA[4];
  {
    int row = row0 + rbase + llo;
#pragma unroll
    for (int kf=0; kf<4; ++kf){
      const float* p = previous + (size_t)row*ND + kf*32 + lhi*8;
      float4 f0 = *(const float4*)p;
      float4 f1 = *(const float4*)(p+4);
      bf16x8 v;
      v[0]=(__bf16)f0.x; v[1]=(__bf16)f0.y; v[2]=(__bf16)f0.z; v[3]=(__bf16)f0.w;
      v[4]=(__bf16)f1.x; v[5]=(__bf16)f1.y; v[6]=(__bf16)f1.z; v[7]=(__bf16)f1.w;
      prevA[kf] = v;
    }
  }

  float curC[8][4];           // current, C-layout, fp32 master
  f32x4 accv[8];              // accumulated output
  float active[4], depth[4], smass[4], gsum[4], dsum[4], asum[4];
#pragma unroll
  for (int cf=0; cf<8; ++cf){
    accv[cf] = (f32x4){0.f,0.f,0.f,0.f};
#pragma unroll
    for (int r=0; r<4; ++r){
      int row = row0 + rbase + lhi*4 + r;
      curC[cf][r] = signal[(size_t)row*ND + cf*16 + llo];
    }
  }
#pragma unroll
  for (int r=0; r<4; ++r){
    active[r]=1.f; depth[r]=0.f; smass[r]=0.f;
    gsum[r]=0.f; dsum[r]=0.f; asum[r]=0.f;
  }

#pragma unroll 1
  for (int l=0; l<NL; ++l){
    // stage Wg (slot 2l) into wbuf (wbuf free: S4 of prev level)
    {
      const char* src = (const char*)wpk + (size_t)(l*2 + 0)*65536;
      char* dstb = (char*)wbuf;
#pragma unroll
      for (int i=0;i<16;++i){
        int off = i*4096 + tid*16;
        gload16(src + off, dstb + off);
      }
    }
    // write current into tile (bf16, swizzled: byte ^= (row&7)<<4) — wave-private rows
#pragma unroll
    for (int cf=0; cf<8; ++cf)
#pragma unroll
      for (int r=0; r<4; ++r){
        int rowl = rbase + lhi*4 + r;
        int byte = ((cf*16 + llo)*2) ^ ((rowl & 7) << 4);
        tile[rowl*128 + (byte>>1)] = bfbits(curC[cf][r]);
      }
    // wave-local write->read coherence (same wave owns these 16 rows)
    asm volatile("s_waitcnt lgkmcnt(0)" ::: "memory");
    __builtin_amdgcn_sched_barrier(0);
    bf16x8 curA[4];
    {
      int rowl = rbase + llo;
      const char* base = (const char*)tile + rowl*256;
      int sw = (rowl & 7) << 4;
#pragma unroll
      for (int kf=0; kf<4; ++kf){
        int byte = (kf*64 + lhi*16) ^ sw;
        curA[kf] = __builtin_bit_cast(bf16x8, *(const uint4*)(base + byte));
      }
    }
    __syncthreads();                       // S1: Wg staged (drains vmcnt)

    f32x4 pacc[8];
    auto zero_acc = [&](){
#pragma unroll
      for (int cf=0; cf<8; ++cf) pacc[cf] = (f32x4){0.f,0.f,0.f,0.f};
    };
    auto run_gemm = [&](){
#pragma unroll
      for (int kf=0; kf<4; ++kf){
        bf16x8 a = curA[kf];
#pragma unroll
        for (int cf=0; cf<8; ++cf){
          bf16x8 b = __builtin_bit_cast(bf16x8, wbuf[(kf*8+cf)*64 + lane]);
          pacc[cf] = __builtin_amdgcn_mfma_f32_16x16x32_bf16(a, b, pacc[cf], 0,0,0);
        }
      }
#pragma unroll
      for (int kp=0; kp<4; ++kp){
        bf16x8 a = prevA[kp];
#pragma unroll
        for (int cf=0; cf<8; ++cf){
          bf16x8 b = __builtin_bit_cast(bf16x8, wbuf[((kp+4)*8+cf)*64 + lane]);
          pacc[cf] = __builtin_amdgcn_mfma_f32_16x16x32_bf16(a, b, pacc[cf], 0,0,0);
        }
      }
    };

    // ---- gate GEMM ----
    zero_acc();
    run_gemm();
    __syncthreads();                       // S2: all waves done reading Wg

    // stage Wp (slot 2l+1) — issued before gate elementwise so it overlaps VALU
    {
      const char* src = (const char*)wpk + (size_t)(l*2 + 1)*65536;
      char* dstb = (char*)wbuf;
#pragma unroll
      for (int i=0;i<16;++i){
        int off = i*4096 + tid*16;
        gload16(src + off, dstb + off);
      }
    }

    // ---- gate elementwise (overlaps Wp staging) ----
    unsigned int gstash[8][2];
    {
      float gpart[4] = {0.f,0.f,0.f,0.f};
#pragma unroll
      for (int cf=0; cf<8; ++cf){
        float bgv = bg[l*ND + cf*16 + llo];
        float g0 = sigm(pacc[cf][0] + bgv);
        float g1 = sigm(pacc[cf][1] + bgv);
        float g2 = sigm(pacc[cf][2] + bgv);
        float g3 = sigm(pacc[cf][3] + bgv);
        gpart[0]+=g0; gpart[1]+=g1; gpart[2]+=g2; gpart[3]+=g3;
        gstash[cf][0] = pk2(g0,g1);
        gstash[cf][1] = pk2(g2,g3);
      }
#pragma unroll
      for (int r=0; r<4; ++r)
        gsum[r] += red16(gpart[r]) * (1.0f/ND);
    }
    __syncthreads();                       // S3: Wp staged (drains vmcnt)

    // ---- candidate GEMM ----
    zero_acc();
    run_gemm();
    __syncthreads();                       // S4: all waves done reading Wp -> wbuf free

    // ---- elementwise update + LN + stats (pure register work) ----
    float s1[4] = {0.f,0.f,0.f,0.f};
    float s2[4] = {0.f,0.f,0.f,0.f};
#pragma unroll
    for (int cf=0; cf<8; ++cf){
      float bpv = bp[l*ND + cf*16 + llo];
#pragma unroll
      for (int r=0; r<4; ++r){
        float cand = tanhfast(pacc[cf][r] + bpv);
        float c = curC[cf][r];
        BFP gp; gp.u = gstash[cf][r>>1];
        float g = (float)gp.h[r&1];
        float x = c + g*(cand - c);
        pacc[cf][r] = x;
        s1[r] += x; s2[r] += x*x;
      }
    }
    float mu[4], inv[4];
#pragma unroll
    for (int r=0; r<4; ++r){
      float m = red16(s1[r]) * (1.0f/ND);
      float q = red16(s2[r]) * (1.0f/ND);
      mu[r] = m;
      inv[r] = rsqrtf(q - m*m + 1e-5f);
    }
    float dpart[4] = {0.f,0.f,0.f,0.f};
    float apart[4] = {0.f,0.f,0.f,0.f};
#pragma unroll
    for (int cf=0; cf<8; ++cf){
      float gm = gamma[l*ND + cf*16 + llo];
      float bt = beta [l*ND + cf*16 + llo];
      float wv = Ws[l*256 + cf*16 + llo];
#pragma unroll
      for (int r=0; r<4; ++r){
        float un = (pacc[cf][r] - mu[r])*inv[r]*gm + bt;
        float c = curC[cf][r];
        float df = un - c;
        dpart[r] += df*df;
        apart[r] += un*wv;
        pacc[cf][r] = un;
      }
    }
    float smrow[4];
#pragma unroll
    for (int r=0; r<4; ++r){
      float dd = red16(dpart[r]);
      float av = red16(apart[r]);
      int row = row0 + rbase + lhi*4 + r;
      float adq = sigm(av + pdot[row*NL + l]);
      float sp  = sigm((adq - 0.6f)*10.0f);
      float sm  = active[r]*sp;
      asum[r] += adq;
      dsum[r] += sqrtf(dd);
      depth[r] += sm * (float)(l+1);
      smass[r] += sm;
      active[r] *= (1.0f - sp);
      smrow[r] = sm;
    }
#pragma unroll
    for (int cf=0; cf<8; ++cf)
#pragma unroll
      for (int r=0; r<4; ++r){
        float un = pacc[cf][r];
        accv[cf][r] += smrow[r]*un;
        curC[cf][r] = un;
      }
  }

  // ---- outputs ----
#pragma unroll
  for (int cf=0; cf<8; ++cf)
#pragma unroll
    for (int r=0; r<4; ++r){
      int row = row0 + rbase + lhi*4 + r;
      out[(size_t)row*ND + cf*16 + llo] = accv[cf][r] + active[r]*curC[cf][r];
    }
  if (llo == 0){
    const size_t BD = (size_t)NB*ND;
#pragma unroll
    for (int r=0; r<4; ++r){
      int row = row0 + rbase + lhi*4 + r;
      out[BD + row]                = gsum[r]*(1.0f/NL);
      out[BD + NB + row]           = dsum[r]*(1.0f/NL);
      out[BD + 2*(size_t)NB + row] = depth[r] + active[r]*(float)NL;
      out[BD + 3*(size_t)NB + row] = smass[r];
      out[BD + 4*(size_t)NB + row] = asum[r]*(1.0f/NL);
    }
  }
}

extern "C" void kernel_launch(void* const* d_in, const int* in_sizes, int n_in,
                              void* d_out, int out_size, void* d_ws, size_t ws_size,
                              hipStream_t stream){
  const float* signal   = (const float*)d_in[0];
  const float* previous = (const float*)d_in[1];
  const float* Wp    = (const float*)d_in[2];
  const float* bp    = (const float*)d_in[3];
  const float* Wg    = (const float*)d_in[4];
  const float* bg    = (const float*)d_in[5];
  const float* Ws    = (const float*)d_in[6];
  const float* bs    = (const float*)d_in[7];
  const float* gamma = (const float*)d_in[8];
  const float* beta  = (const float*)d_in[9];

  uint4* wpk  = (uint4*)d_ws;                                   // 1 MB packed weights
  float* pdot = (float*)((char*)d_ws + (size_t)NL*2*65536);     // 8 MB prevdot

  repack_w<<<256, 256, 0, stream>>>(Wp, Wg, wpk);
  prevdot_k<<<NB/16, 256, 0, stream>>>(previous, Ws, bs, pdot);
  fused_k<<<NB/64, 256, 0, stream>>>(signal, previous, bp, bg, Ws, gamma, beta,
                                     wpk, pdot, (float*)d_out);
}